// Round 7
// baseline (28.767 us; speedup 1.0000x reference)
//
#include <hip/hip_runtime.h>
#include <math.h>

// BrownianKernelLayer: K[i,j] = 0.5 * sum_d (|x_id|^p + |X2_jd|^p - |x_id - X2_jd|^p)
// p = 2 * softplus(log_H).  N=M=2048, D=16, fp32 in/out.
//
// v7 = v6 structure + HYBRID pipe-balancing: per 4x2 micro-tile and d,
// 6 terms use the trans path (sub, v_log, mul, v_exp, add) and 2 terms use a
// pure-VALU path (bit-split log2 with deg-4 runtime Chebyshev phi(m) [v5-
// validated numerics], exp2 via floor + deg-3 poly 2^f + v_ldexp).
// If the trans pipe executes asynchronously w.r.t. VALU issue, this balances
// trans-pipe (96 cyc/8 terms) against VALU-pipe (104 cyc/8 terms) -> ~1.6x.
// If trans blocks the SIMD issue port, this mildly regresses -> discriminator.

#define D_DIM 16
#define BR 64   // rows per tile (x)
#define BC 32   // cols per tile (X2)

__device__ __forceinline__ float powp(float t, float p) {
    // t >= 0; t^p = exp2(p*log2(t)); log2(0) = -inf -> exp2 -> 0 (correct)
    return __builtin_amdgcn_exp2f(p * __builtin_amdgcn_logf(t));
}

__device__ __forceinline__ float sconst(float v) {
    return __uint_as_float(__builtin_amdgcn_readfirstlane(__float_as_uint(v)));
}

__global__ __launch_bounds__(256) void fbm_kernel(
    const float* __restrict__ x,    // [N, 16]
    const float* __restrict__ X2,   // [M, 16]
    const float* __restrict__ logH, // [1]
    float* __restrict__ out,        // [N, M]
    int N, int M)
{
    __shared__ float xs[D_DIM][BR];   // transposed x tile
    __shared__ float ys[D_DIM][BC];   // transposed X2 tile
    __shared__ float t1s[BR];
    __shared__ float t2s[BC];

    const int tid  = threadIdx.x;
    const int brow = blockIdx.y * BR;
    const int bcol = blockIdx.x * BC;

    const float H = log1pf(expf(logH[0]));  // softplus(log_H)
    const float p = 2.0f * H;

    // ==== deg-4 Chebyshev fit: phi(m) = log2(m) - (m-1) on [1,2]  (v5-validated)
    const float T1 = 0.475528258f, T2 = 0.293892626f;
    float n0 = 1.5f + T1, n1 = 1.5f + T2, n2 = 1.5f, n3 = 1.5f - T2, n4 = 1.5f - T1;
    float f0 = __builtin_amdgcn_logf(n0) - (n0 - 1.0f);
    float f1 = __builtin_amdgcn_logf(n1) - (n1 - 1.0f);
    float f2 = __builtin_amdgcn_logf(n2) - (n2 - 1.0f);
    float f3 = __builtin_amdgcn_logf(n3) - (n3 - 1.0f);
    float f4 = __builtin_amdgcn_logf(n4) - (n4 - 1.0f);
    float s1 = 0.5f * (f0 + f4), d1 = 0.5f * (f0 - f4);
    float s2 = 0.5f * (f1 + f3), d2 = 0.5f * (f1 - f3);
    float u1 = T1 * T1, u2 = T2 * T2;
    float A = s1 - f2, B = s2 - f2;
    float det = u1 * u2 * (u2 - u1);
    float e1 = (A * u2 * u2 - B * u1 * u1) / det;
    float e2 = (B * u1 - A * u2) / det;
    float Ap = d1 / T1, Bp = d2 / T2;
    float o1 = (Ap - Bp) / (u1 - u2);
    float o0 = Ap - o1 * u1;
    float a4 = e2;
    float a3 = o1 - 6.0f * e2;
    float a2 = e1 - 4.5f * o1 + 13.5f * e2;
    float a1 = o0 - 3.0f * e1 + 6.75f * o1 - 13.5f * e2;
    float a0 = f2 - 1.5f * o0 + 2.25f * e1 - 3.375f * o1 + 5.0625f * e2;
    const float q4 = sconst(p * a4);
    const float q3 = sconst(p * a3);
    const float q2 = sconst(p * a2);
    const float q1 = sconst(p * a1);
    const float q0 = sconst(p * a0 - 127.0f * p);
    const float HB = sconst(p * (1.0f / 8388608.0f));   // p * 2^-23

    // ==== deg-3 Chebyshev fit: 2^f on [0,1]
    {
        // reuse names in a scope to avoid VGPR bloat
    }
    const float ZA = 0.461939766f, ZB = 0.191341716f;
    float g0 = __builtin_amdgcn_exp2f(0.5f + ZA);
    float g1 = __builtin_amdgcn_exp2f(0.5f + ZB);
    float g2 = __builtin_amdgcn_exp2f(0.5f - ZB);
    float g3 = __builtin_amdgcn_exp2f(0.5f - ZA);
    float sa = 0.5f * (g0 + g3), da = 0.5f * (g0 - g3);
    float sb = 0.5f * (g1 + g2), db = 0.5f * (g1 - g2);
    float w1 = ZA * ZA, w2 = ZB * ZB;
    float ee1 = (sa - sb) / (w1 - w2);
    float ee0 = sa - ee1 * w1;
    float Ag = da / ZA, Bg = db / ZB;
    float oo1 = (Ag - Bg) / (w1 - w2);
    float oo0 = Ag - oo1 * w1;
    // shift w = f - 0.5 to monomial in f
    const float b3 = sconst(oo1);
    const float b2 = sconst(ee1 - 1.5f * oo1);
    const float b1 = sconst(oo0 - ee1 + 0.75f * oo1);
    const float b0 = sconst(ee0 - 0.5f * oo0 + 0.25f * ee1 - 0.125f * oo1);

    // ---- stage x tile: 64 rows x 16 d = 1024 floats = 256 x float4
    {
        float4 vx = ((const float4*)(x + (size_t)brow * D_DIM))[tid];
        int r  = tid >> 2;
        int d0 = (tid & 3) << 2;
        xs[d0 + 0][r] = vx.x; xs[d0 + 1][r] = vx.y;
        xs[d0 + 2][r] = vx.z; xs[d0 + 3][r] = vx.w;
    }
    // ---- stage X2 tile: 32 rows x 16 d = 512 floats = 128 x float4
    if (tid < 128) {
        float4 vy = ((const float4*)(X2 + (size_t)bcol * D_DIM))[tid];
        int r  = tid >> 2;
        int d0 = (tid & 3) << 2;
        ys[d0 + 0][r] = vy.x; ys[d0 + 1][r] = vy.y;
        ys[d0 + 2][r] = vy.z; ys[d0 + 3][r] = vy.w;
    }
    __syncthreads();

    // ---- per-row self terms (trans path; tiny)
    if (tid < BR) {
        float s = 0.0f;
        #pragma unroll
        for (int d = 0; d < D_DIM; ++d) s += powp(fabsf(xs[d][tid]), p);
        t1s[tid] = s;
    } else if (tid < BR + BC) {
        int r = tid - BR;
        float s = 0.0f;
        #pragma unroll
        for (int d = 0; d < D_DIM; ++d) s += powp(fabsf(ys[d][r]), p);
        t2s[r] = s;
    }
    __syncthreads();

    // ---- main: 4x2 outputs per thread; 16x16 thread grid covers 64x32
    const int ti = tid >> 4;
    const int tj = tid & 15;

    float acc[4][2] = {};

    // pure-VALU |u|^p: bit-split log2 + poly exp2 (17 VALU, 0 trans)
    #define PTERM(A_, B_, DST_) { \
        float u_ = (A_) - (B_); \
        unsigned ba_ = __float_as_uint(u_) & 0x7FFFFFFFu; \
        float bf_ = (float)ba_; \
        float mm_ = __uint_as_float((ba_ & 0x007FFFFFu) | 0x3F800000u); \
        float ph_ = fmaf(fmaf(fmaf(fmaf(q4, mm_, q3), mm_, q2), mm_, q1), mm_, q0); \
        float arg_ = fmaf(bf_, HB, ph_); \
        float fl_ = floorf(arg_); \
        float fr_ = arg_ - fl_; \
        int   k_  = (int)fl_; \
        float e_  = fmaf(fmaf(fmaf(b3, fr_, b2), fr_, b1), fr_, b0); \
        DST_ += ldexpf(e_, k_); }

    #pragma unroll 4
    for (int d = 0; d < D_DIM; ++d) {
        float4 xa = *(const float4*)&xs[d][ti * 4];
        float2 xb = *(const float2*)&ys[d][tj * 2];
        float A0 = xa.x, A1 = xa.y, A2 = xa.z, A3 = xa.w;
        float B0 = xb.x, B1 = xb.y;

        // 6 terms on the trans pipe
        acc[0][0] += powp(fabsf(A0 - B0), p);
        acc[0][1] += powp(fabsf(A0 - B1), p);
        acc[1][0] += powp(fabsf(A1 - B0), p);
        acc[1][1] += powp(fabsf(A1 - B1), p);
        acc[2][0] += powp(fabsf(A2 - B0), p);
        acc[2][1] += powp(fabsf(A2 - B1), p);
        // 2 terms on the VALU pipe
        PTERM(A3, B0, acc[3][0])
        PTERM(A3, B1, acc[3][1])
    }
    #undef PTERM

    // ---- epilogue: K = 0.5*(t1[i] + t2[j] - t3)
    float t2v0 = t2s[tj * 2 + 0];
    float t2v1 = t2s[tj * 2 + 1];

    #pragma unroll
    for (int a = 0; a < 4; ++a) {
        float t1v = t1s[ti * 4 + a];
        float2 o;
        o.x = 0.5f * (t1v + t2v0 - acc[a][0]);
        o.y = 0.5f * (t1v + t2v1 - acc[a][1]);
        int gi = brow + ti * 4 + a;
        *(float2*)(out + (size_t)gi * M + bcol + tj * 2) = o;
    }
}

extern "C" void kernel_launch(void* const* d_in, const int* in_sizes, int n_in,
                              void* d_out, int out_size, void* d_ws, size_t ws_size,
                              hipStream_t stream) {
    const float* x    = (const float*)d_in[0];
    const float* X2   = (const float*)d_in[1];
    const float* logH = (const float*)d_in[2];
    float* out = (float*)d_out;

    int N = in_sizes[0] / D_DIM;
    int M = in_sizes[1] / D_DIM;

    dim3 grid(M / BC, N / BR);
    dim3 block(256);
    fbm_kernel<<<grid, block, 0, stream>>>(x, X2, logH, out, N, M);
}